// Round 1
// baseline (4443.920 us; speedup 1.0000x reference)
//
#include <hip/hip_runtime.h>

#define N_USERS 100000
#define N_ITEMS 200000
#define N_NODES 300000
#define DIM 64

// total fp32 elements in the node-embedding matrix
#define TOT_ELEMS ((size_t)N_NODES * DIM)          // 19,200,000
#define TOT_F4    (TOT_ELEMS / 4)                  // 4,800,000
#define USER_F4   (((size_t)N_USERS * DIM) / 4)    // 1,600,000

// x = concat(user,item); out = 0.25*x; y = 0
__global__ void init_kernel(const float4* __restrict__ user,
                            const float4* __restrict__ item,
                            float4* __restrict__ x,
                            float4* __restrict__ y,
                            float4* __restrict__ out) {
    size_t i = (size_t)blockIdx.x * blockDim.x + threadIdx.x;
    if (i >= TOT_F4) return;
    float4 v = (i < USER_F4) ? user[i] : item[i - USER_F4];
    x[i] = v;
    float4 o;
    o.x = 0.25f * v.x; o.y = 0.25f * v.y; o.z = 0.25f * v.z; o.w = 0.25f * v.w;
    out[i] = o;
    float4 z; z.x = 0.f; z.y = 0.f; z.z = 0.f; z.w = 0.f;
    y[i] = z;
}

// One edge per wave: lane d handles dim d.
// y[rows[e]*64 + d] += vals[e] * x[cols[e]*64 + d]
__global__ void spmm_kernel(const int* __restrict__ rows,
                            const int* __restrict__ cols,
                            const float* __restrict__ vals,
                            const float* __restrict__ x,
                            float* __restrict__ y,
                            int nnz) {
    size_t t = (size_t)blockIdx.x * blockDim.x + threadIdx.x;
    int e = (int)(t >> 6);
    int d = (int)(t & 63);
    if (e >= nnz) return;
    int r = rows[e];
    int c = cols[e];
    float v = vals[e];
    float g = v * x[(size_t)c * DIM + d];
    unsafeAtomicAdd(&y[(size_t)r * DIM + d], g);
}

// out += 0.25*y; optionally zero xz (the buffer that becomes next layer's target)
__global__ void add_zero_kernel(const float4* __restrict__ y,
                                float4* __restrict__ out,
                                float4* __restrict__ xz,
                                int do_zero) {
    size_t i = (size_t)blockIdx.x * blockDim.x + threadIdx.x;
    if (i >= TOT_F4) return;
    float4 a = y[i];
    float4 o = out[i];
    o.x += 0.25f * a.x; o.y += 0.25f * a.y; o.z += 0.25f * a.z; o.w += 0.25f * a.w;
    out[i] = o;
    if (do_zero) {
        float4 z; z.x = 0.f; z.y = 0.f; z.z = 0.f; z.w = 0.f;
        xz[i] = z;
    }
}

extern "C" void kernel_launch(void* const* d_in, const int* in_sizes, int n_in,
                              void* d_out, int out_size, void* d_ws, size_t ws_size,
                              hipStream_t stream) {
    const float* user = (const float*)d_in[0];
    const float* item = (const float*)d_in[1];
    const int*   rows = (const int*)d_in[2];
    const int*   cols = (const int*)d_in[3];
    const float* vals = (const float*)d_in[4];
    int nnz = in_sizes[2];

    float* out = (float*)d_out;
    float* x = (float*)d_ws;                 // 76.8 MB
    float* y = x + TOT_ELEMS;                // 76.8 MB

    const int BLK = 256;
    int grid_elem = (int)((TOT_F4 + BLK - 1) / BLK);

    init_kernel<<<grid_elem, BLK, 0, stream>>>(
        (const float4*)user, (const float4*)item,
        (float4*)x, (float4*)y, (float4*)out);

    for (int layer = 0; layer < 3; ++layer) {
        size_t threads = (size_t)nnz * 64;
        int grid_spmm = (int)((threads + BLK - 1) / BLK);
        spmm_kernel<<<grid_spmm, BLK, 0, stream>>>(rows, cols, vals, x, y, nnz);
        // after add: out += y/4; zero old x so it can serve as next layer's target
        add_zero_kernel<<<grid_elem, BLK, 0, stream>>>(
            (const float4*)y, (float4*)out, (float4*)x, layer < 2 ? 1 : 0);
        // swap roles: new source is y, new (zeroed) target is old x
        float* tmp = x; x = y; y = tmp;
    }
}

// Round 2
// 2841.054 us; speedup vs baseline: 1.5642x; 1.5642x over previous
//
#include <hip/hip_runtime.h>

#define N_USERS 100000
#define N_ITEMS 200000
#define N_NODES 300000
#define DIM 64
#define NNZ_EXPECT 6400000

#define TOT_ELEMS ((size_t)N_NODES * DIM)          // 19,200,000 floats
#define TOT_F4    (TOT_ELEMS / 4)                  // 4,800,000
#define USER_F4   (((size_t)N_USERS * DIM) / 4)    // 1,600,000

#define CHUNK 1024
#define NCHUNK ((N_NODES + CHUNK - 1) / CHUNK)     // 293

// ---------- init: x = concat(user,item); out = 0.25*x ----------
__global__ void init_kernel(const float4* __restrict__ user,
                            const float4* __restrict__ item,
                            float4* __restrict__ x,
                            float4* __restrict__ out) {
    size_t i = (size_t)blockIdx.x * blockDim.x + threadIdx.x;
    if (i >= TOT_F4) return;
    float4 v = (i < USER_F4) ? user[i] : item[i - USER_F4];
    x[i] = v;
    float4 o;
    o.x = 0.25f * v.x; o.y = 0.25f * v.y; o.z = 0.25f * v.z; o.w = 0.25f * v.w;
    out[i] = o;
}

// ---------- CSR build ----------
__global__ void zero_counts_kernel(int* __restrict__ counts) {
    int i = blockIdx.x * blockDim.x + threadIdx.x;
    if (i < N_NODES) counts[i] = 0;
}

__global__ void hist_kernel(const int* __restrict__ rows, int* __restrict__ counts, int nnz) {
    int e = blockIdx.x * blockDim.x + threadIdx.x;
    if (e < nnz) atomicAdd(&counts[rows[e]], 1);
}

// per-chunk sums (1024 counts per block of 256 threads)
__global__ void scan1_kernel(const int* __restrict__ counts, int* __restrict__ blocksum) {
    __shared__ int s[256];
    int b = blockIdx.x, t = threadIdx.x;
    int base = b * CHUNK + t * 4;
    int v = 0;
    #pragma unroll
    for (int k = 0; k < 4; ++k)
        if (base + k < N_NODES) v += counts[base + k];
    s[t] = v;
    __syncthreads();
    for (int off = 128; off > 0; off >>= 1) {
        if (t < off) s[t] += s[t + off];
        __syncthreads();
    }
    if (t == 0) blocksum[b] = s[0];
}

// exclusive scan of NCHUNK block sums, single block of 512
__global__ void scan2_kernel(const int* __restrict__ blocksum, int* __restrict__ chunk_off) {
    __shared__ int s[512];
    int t = threadIdx.x;
    int orig = (t < NCHUNK) ? blocksum[t] : 0;
    s[t] = orig;
    __syncthreads();
    for (int off = 1; off < 512; off <<= 1) {
        int v = (t >= off) ? s[t - off] : 0;
        __syncthreads();
        s[t] += v;
        __syncthreads();
    }
    if (t < NCHUNK) chunk_off[t] = s[t] - orig;   // exclusive
}

// per-chunk exclusive scan -> row_ptr, cursor
__global__ void scan3_kernel(const int* __restrict__ counts,
                             const int* __restrict__ chunk_off,
                             int* __restrict__ row_ptr,
                             int* __restrict__ cursor,
                             int nnz) {
    __shared__ int s[256];
    int b = blockIdx.x, t = threadIdx.x;
    int base = b * CHUNK + t * 4;
    int c[4];
    int local = 0;
    #pragma unroll
    for (int k = 0; k < 4; ++k) {
        c[k] = (base + k < N_NODES) ? counts[base + k] : 0;
        local += c[k];
    }
    s[t] = local;
    __syncthreads();
    for (int off = 1; off < 256; off <<= 1) {
        int v = (t >= off) ? s[t - off] : 0;
        __syncthreads();
        s[t] += v;
        __syncthreads();
    }
    int p = chunk_off[b] + s[t] - local;  // exclusive prefix for this thread's 4
    #pragma unroll
    for (int k = 0; k < 4; ++k) {
        if (base + k < N_NODES) {
            row_ptr[base + k] = p;
            cursor[base + k] = p;
            p += c[k];
        }
    }
    if (b == 0 && t == 0) row_ptr[N_NODES] = nnz;
}

__global__ void scatter_kernel(const int* __restrict__ rows,
                               const int* __restrict__ cols,
                               const float* __restrict__ vals,
                               int* __restrict__ cursor,
                               int2* __restrict__ sorted,
                               int nnz) {
    int e = blockIdx.x * blockDim.x + threadIdx.x;
    if (e >= nnz) return;
    int r = rows[e];
    int p = atomicAdd(&cursor[r], 1);
    sorted[p] = make_int2(cols[e], __float_as_int(vals[e]));
}

// ---------- row-centric SpMM: one wave per row, lane = dim ----------
// dst[r,:] = sum_e val_e * src[col_e,:];  out[r,:] += 0.25 * dst[r,:]
__global__ void spmm_row_kernel(const int* __restrict__ row_ptr,
                                const int2* __restrict__ sorted,
                                const float* __restrict__ src,
                                float* __restrict__ dst,
                                float* __restrict__ out) {
    int t = blockIdx.x * blockDim.x + threadIdx.x;
    int r = t >> 6;         // wave id = row
    int d = t & 63;         // lane = dim
    if (r >= N_NODES) return;
    int beg = row_ptr[r];
    int end = row_ptr[r + 1];
    float acc = 0.f;
    for (int i = beg; i < end; ++i) {
        int2 e = sorted[i];                       // broadcast (same addr all lanes)
        acc += __int_as_float(e.y) * src[(size_t)e.x * DIM + d];
    }
    size_t o = (size_t)r * DIM + d;
    dst[o] = acc;
    out[o] += 0.25f * acc;
}

extern "C" void kernel_launch(void* const* d_in, const int* in_sizes, int n_in,
                              void* d_out, int out_size, void* d_ws, size_t ws_size,
                              hipStream_t stream) {
    const float* user = (const float*)d_in[0];
    const float* item = (const float*)d_in[1];
    const int*   rows = (const int*)d_in[2];
    const int*   cols = (const int*)d_in[3];
    const float* vals = (const float*)d_in[4];
    int nnz = in_sizes[2];

    float* out = (float*)d_out;

    // workspace layout
    float* x = (float*)d_ws;                         // 76.8 MB
    float* y = x + TOT_ELEMS;                        // 76.8 MB
    int* counts    = (int*)(y + TOT_ELEMS);          // 1.2 MB
    int* cursor    = counts + N_NODES;               // 1.2 MB
    int* row_ptr   = cursor + N_NODES;               // 1.2 MB
    int* blocksum  = row_ptr + (N_NODES + 1);        // 293
    int* chunk_off = blocksum + NCHUNK;              // 293
    // pad to 8B alignment for int2 (total ints so far is even by construction)
    int* pad = chunk_off + NCHUNK;
    uintptr_t addr = (uintptr_t)pad;
    addr = (addr + 7) & ~(uintptr_t)7;
    int2* sorted = (int2*)addr;                      // 51.2 MB

    const int BLK = 256;
    int grid_elem = (int)((TOT_F4 + BLK - 1) / BLK);          // 18750
    int grid_node = (N_NODES + BLK - 1) / BLK;                // 1172
    int grid_edge = (nnz + BLK - 1) / BLK;                    // 25000
    int grid_rows = (N_NODES * 64 + BLK - 1) / BLK;           // 75000

    init_kernel<<<grid_elem, BLK, 0, stream>>>(
        (const float4*)user, (const float4*)item, (float4*)x, (float4*)out);

    // CSR build
    zero_counts_kernel<<<grid_node, BLK, 0, stream>>>(counts);
    hist_kernel<<<grid_edge, BLK, 0, stream>>>(rows, counts, nnz);
    scan1_kernel<<<NCHUNK, BLK, 0, stream>>>(counts, blocksum);
    scan2_kernel<<<1, 512, 0, stream>>>(blocksum, chunk_off);
    scan3_kernel<<<NCHUNK, BLK, 0, stream>>>(counts, chunk_off, row_ptr, cursor, nnz);
    scatter_kernel<<<grid_edge, BLK, 0, stream>>>(rows, cols, vals, cursor, sorted, nnz);

    // 3 propagation layers, ping-pong x/y, fused out accumulation
    float* src = x;
    float* dst = y;
    for (int layer = 0; layer < 3; ++layer) {
        spmm_row_kernel<<<grid_rows, BLK, 0, stream>>>(row_ptr, sorted, src, dst, out);
        float* tmp = src; src = dst; dst = tmp;
    }
}

// Round 3
// 1686.325 us; speedup vs baseline: 2.6353x; 1.6848x over previous
//
#include <hip/hip_runtime.h>

#define N_USERS 100000
#define N_ITEMS 200000
#define N_NODES 300000
#define DIM 64
#define NNZ_EXPECT 6400000

#define TOT_ELEMS ((size_t)N_NODES * DIM)          // 19,200,000 floats
#define TOT_F4    (TOT_ELEMS / 4)                  // 4,800,000
#define USER_F4   (((size_t)N_USERS * DIM) / 4)    // 1,600,000

#define CHUNK 1024
#define NCHUNK ((N_NODES + CHUNK - 1) / CHUNK)     // 293

// ---------- init: x = concat(user,item); out = 0.25*x ----------
__global__ void init_kernel(const float4* __restrict__ user,
                            const float4* __restrict__ item,
                            float4* __restrict__ x,
                            float4* __restrict__ out) {
    size_t i = (size_t)blockIdx.x * blockDim.x + threadIdx.x;
    if (i >= TOT_F4) return;
    float4 v = (i < USER_F4) ? user[i] : item[i - USER_F4];
    x[i] = v;
    float4 o;
    o.x = 0.25f * v.x; o.y = 0.25f * v.y; o.z = 0.25f * v.z; o.w = 0.25f * v.w;
    out[i] = o;
}

// ---------- CSR build ----------
__global__ void zero_counts_kernel(int* __restrict__ counts) {
    int i = blockIdx.x * blockDim.x + threadIdx.x;
    if (i < N_NODES) counts[i] = 0;
}

__global__ void hist_kernel(const int* __restrict__ rows, int* __restrict__ counts, int nnz) {
    int e = blockIdx.x * blockDim.x + threadIdx.x;
    if (e < nnz) atomicAdd(&counts[rows[e]], 1);
}

// per-chunk sums (1024 counts per block of 256 threads)
__global__ void scan1_kernel(const int* __restrict__ counts, int* __restrict__ blocksum) {
    __shared__ int s[256];
    int b = blockIdx.x, t = threadIdx.x;
    int base = b * CHUNK + t * 4;
    int v = 0;
    #pragma unroll
    for (int k = 0; k < 4; ++k)
        if (base + k < N_NODES) v += counts[base + k];
    s[t] = v;
    __syncthreads();
    for (int off = 128; off > 0; off >>= 1) {
        if (t < off) s[t] += s[t + off];
        __syncthreads();
    }
    if (t == 0) blocksum[b] = s[0];
}

// exclusive scan of NCHUNK block sums, single block of 512
__global__ void scan2_kernel(const int* __restrict__ blocksum, int* __restrict__ chunk_off) {
    __shared__ int s[512];
    int t = threadIdx.x;
    int orig = (t < NCHUNK) ? blocksum[t] : 0;
    s[t] = orig;
    __syncthreads();
    for (int off = 1; off < 512; off <<= 1) {
        int v = (t >= off) ? s[t - off] : 0;
        __syncthreads();
        s[t] += v;
        __syncthreads();
    }
    if (t < NCHUNK) chunk_off[t] = s[t] - orig;   // exclusive
}

// per-chunk exclusive scan -> row_ptr, cursor
__global__ void scan3_kernel(const int* __restrict__ counts,
                             const int* __restrict__ chunk_off,
                             int* __restrict__ row_ptr,
                             int* __restrict__ cursor,
                             int nnz) {
    __shared__ int s[256];
    int b = blockIdx.x, t = threadIdx.x;
    int base = b * CHUNK + t * 4;
    int c[4];
    int local = 0;
    #pragma unroll
    for (int k = 0; k < 4; ++k) {
        c[k] = (base + k < N_NODES) ? counts[base + k] : 0;
        local += c[k];
    }
    s[t] = local;
    __syncthreads();
    for (int off = 1; off < 256; off <<= 1) {
        int v = (t >= off) ? s[t - off] : 0;
        __syncthreads();
        s[t] += v;
        __syncthreads();
    }
    int p = chunk_off[b] + s[t] - local;  // exclusive prefix for this thread's 4
    #pragma unroll
    for (int k = 0; k < 4; ++k) {
        if (base + k < N_NODES) {
            row_ptr[base + k] = p;
            cursor[base + k] = p;
            p += c[k];
        }
    }
    if (b == 0 && t == 0) row_ptr[N_NODES] = nnz;
}

__global__ void scatter_kernel(const int* __restrict__ rows,
                               const int* __restrict__ cols,
                               const float* __restrict__ vals,
                               int* __restrict__ cursor,
                               int2* __restrict__ sorted,
                               int nnz) {
    int e = blockIdx.x * blockDim.x + threadIdx.x;
    if (e >= nnz) return;
    int r = rows[e];
    int p = atomicAdd(&cursor[r], 1);
    sorted[p] = make_int2(cols[e], __float_as_int(vals[e]));
}

// ---------- row-centric SpMM: one wave per row, lane = dim ----------
// Coalesced edge-list load + readlane broadcast + 8-deep gather pipelining.
// dst[r,:] = sum_e val_e * src[col_e,:];  out[r,:] += 0.25 * dst[r,:]
__global__ void spmm_row_kernel(const int* __restrict__ row_ptr,
                                const int2* __restrict__ sorted,
                                const float* __restrict__ src,
                                float* __restrict__ dst,
                                float* __restrict__ out) {
    int t = blockIdx.x * blockDim.x + threadIdx.x;
    int r = t >> 6;         // wave id = row
    int d = t & 63;         // lane = dim
    if (r >= N_NODES) return;
    int beg = row_ptr[r];
    int end = row_ptr[r + 1];
    float acc = 0.f;

    for (int base = beg; base < end; base += 64) {
        int cnt = end - base;
        if (cnt > 64) cnt = 64;
        // coalesced load of up to 64 edges (one per lane)
        int   c_l = 0;
        float v_l = 0.f;
        if (base + d < end) {
            int2 e = sorted[base + d];
            c_l = e.x;
            v_l = __int_as_float(e.y);
        }
        int j = 0;
        // 8 independent gathers in flight
        for (; j + 8 <= cnt; j += 8) {
            int c0 = __shfl(c_l, j + 0), c1 = __shfl(c_l, j + 1);
            int c2 = __shfl(c_l, j + 2), c3 = __shfl(c_l, j + 3);
            int c4 = __shfl(c_l, j + 4), c5 = __shfl(c_l, j + 5);
            int c6 = __shfl(c_l, j + 6), c7 = __shfl(c_l, j + 7);
            float v0 = __shfl(v_l, j + 0), v1 = __shfl(v_l, j + 1);
            float v2 = __shfl(v_l, j + 2), v3 = __shfl(v_l, j + 3);
            float v4 = __shfl(v_l, j + 4), v5 = __shfl(v_l, j + 5);
            float v6 = __shfl(v_l, j + 6), v7 = __shfl(v_l, j + 7);
            float s0 = src[(size_t)c0 * DIM + d];
            float s1 = src[(size_t)c1 * DIM + d];
            float s2 = src[(size_t)c2 * DIM + d];
            float s3 = src[(size_t)c3 * DIM + d];
            float s4 = src[(size_t)c4 * DIM + d];
            float s5 = src[(size_t)c5 * DIM + d];
            float s6 = src[(size_t)c6 * DIM + d];
            float s7 = src[(size_t)c7 * DIM + d];
            acc += v0 * s0; acc += v1 * s1; acc += v2 * s2; acc += v3 * s3;
            acc += v4 * s4; acc += v5 * s5; acc += v6 * s6; acc += v7 * s7;
        }
        // 4-wide remainder
        for (; j + 4 <= cnt; j += 4) {
            int c0 = __shfl(c_l, j + 0), c1 = __shfl(c_l, j + 1);
            int c2 = __shfl(c_l, j + 2), c3 = __shfl(c_l, j + 3);
            float v0 = __shfl(v_l, j + 0), v1 = __shfl(v_l, j + 1);
            float v2 = __shfl(v_l, j + 2), v3 = __shfl(v_l, j + 3);
            float s0 = src[(size_t)c0 * DIM + d];
            float s1 = src[(size_t)c1 * DIM + d];
            float s2 = src[(size_t)c2 * DIM + d];
            float s3 = src[(size_t)c3 * DIM + d];
            acc += v0 * s0; acc += v1 * s1; acc += v2 * s2; acc += v3 * s3;
        }
        for (; j < cnt; ++j) {
            int c = __shfl(c_l, j);
            float v = __shfl(v_l, j);
            acc += v * src[(size_t)c * DIM + d];
        }
    }
    size_t o = (size_t)r * DIM + d;
    dst[o] = acc;
    out[o] += 0.25f * acc;
}

extern "C" void kernel_launch(void* const* d_in, const int* in_sizes, int n_in,
                              void* d_out, int out_size, void* d_ws, size_t ws_size,
                              hipStream_t stream) {
    const float* user = (const float*)d_in[0];
    const float* item = (const float*)d_in[1];
    const int*   rows = (const int*)d_in[2];
    const int*   cols = (const int*)d_in[3];
    const float* vals = (const float*)d_in[4];
    int nnz = in_sizes[2];

    float* out = (float*)d_out;

    // workspace layout
    float* x = (float*)d_ws;                         // 76.8 MB
    float* y = x + TOT_ELEMS;                        // 76.8 MB
    int* counts    = (int*)(y + TOT_ELEMS);          // 1.2 MB
    int* cursor    = counts + N_NODES;               // 1.2 MB
    int* row_ptr   = cursor + N_NODES;               // 1.2 MB
    int* blocksum  = row_ptr + (N_NODES + 1);        // 293
    int* chunk_off = blocksum + NCHUNK;              // 293
    int* pad = chunk_off + NCHUNK;
    uintptr_t addr = (uintptr_t)pad;
    addr = (addr + 7) & ~(uintptr_t)7;
    int2* sorted = (int2*)addr;                      // 51.2 MB

    const int BLK = 256;
    int grid_elem = (int)((TOT_F4 + BLK - 1) / BLK);          // 18750
    int grid_node = (N_NODES + BLK - 1) / BLK;                // 1172
    int grid_edge = (nnz + BLK - 1) / BLK;                    // 25000
    int grid_rows = (N_NODES * 64 + BLK - 1) / BLK;           // 75000

    init_kernel<<<grid_elem, BLK, 0, stream>>>(
        (const float4*)user, (const float4*)item, (float4*)x, (float4*)out);

    // CSR build
    zero_counts_kernel<<<grid_node, BLK, 0, stream>>>(counts);
    hist_kernel<<<grid_edge, BLK, 0, stream>>>(rows, counts, nnz);
    scan1_kernel<<<NCHUNK, BLK, 0, stream>>>(counts, blocksum);
    scan2_kernel<<<1, 512, 0, stream>>>(blocksum, chunk_off);
    scan3_kernel<<<NCHUNK, BLK, 0, stream>>>(counts, chunk_off, row_ptr, cursor, nnz);
    scatter_kernel<<<grid_edge, BLK, 0, stream>>>(rows, cols, vals, cursor, sorted, nnz);

    // 3 propagation layers, ping-pong x/y, fused out accumulation
    float* src = x;
    float* dst = y;
    for (int layer = 0; layer < 3; ++layer) {
        spmm_row_kernel<<<grid_rows, BLK, 0, stream>>>(row_ptr, sorted, src, dst, out);
        float* tmp = src; src = dst; dst = tmp;
    }
}

// Round 4
// 1154.127 us; speedup vs baseline: 3.8505x; 1.4611x over previous
//
#include <hip/hip_runtime.h>
#include <hip/hip_bf16.h>

#define N_USERS 100000
#define N_ITEMS 200000
#define N_NODES 300000
#define DIM 64

#define TOT_ELEMS ((size_t)N_NODES * DIM)          // 19,200,000 floats
#define TOT_F4    (TOT_ELEMS / 4)                  // 4,800,000
#define USER_F4   (((size_t)N_USERS * DIM) / 4)    // 1,600,000

#define CHUNK 1024
#define NCHUNK ((N_NODES + CHUNK - 1) / CHUNK)     // 293

#define BROWS 512
#define NBUCKET ((N_NODES + BROWS - 1) / BROWS)    // 586
#define EPT 32
#define EDGES_PER_BLOCK (EPT * 256)                // 8192

__device__ __forceinline__ float bf2f(unsigned short u) {
    return __uint_as_float((unsigned int)u << 16);
}
__device__ __forceinline__ unsigned short f2bf(float f) {
    __hip_bfloat16 h = __float2bfloat16(f);   // RNE
    return *reinterpret_cast<unsigned short*>(&h);
}

// ---------- init: out = 0.25*concat(user,item); xh = bf16(concat) ----------
__global__ void init_kernel(const float4* __restrict__ user,
                            const float4* __restrict__ item,
                            float4* __restrict__ out,
                            ushort4* __restrict__ xh) {
    size_t i = (size_t)blockIdx.x * blockDim.x + threadIdx.x;
    if (i >= TOT_F4) return;
    float4 v = (i < USER_F4) ? user[i] : item[i - USER_F4];
    float4 o;
    o.x = 0.25f * v.x; o.y = 0.25f * v.y; o.z = 0.25f * v.z; o.w = 0.25f * v.w;
    out[i] = o;
    ushort4 h;
    h.x = f2bf(v.x); h.y = f2bf(v.y); h.z = f2bf(v.z); h.w = f2bf(v.w);
    xh[i] = h;
}

// ---------- CSR row_ptr build ----------
__global__ void zero_counts_kernel(int* __restrict__ counts) {
    int i = blockIdx.x * blockDim.x + threadIdx.x;
    if (i < N_NODES) counts[i] = 0;
}

__global__ void hist_kernel(const int* __restrict__ rows, int* __restrict__ counts, int nnz) {
    int e = blockIdx.x * blockDim.x + threadIdx.x;
    if (e < nnz) atomicAdd(&counts[rows[e]], 1);
}

__global__ void scan1_kernel(const int* __restrict__ counts, int* __restrict__ blocksum) {
    __shared__ int s[256];
    int b = blockIdx.x, t = threadIdx.x;
    int base = b * CHUNK + t * 4;
    int v = 0;
    #pragma unroll
    for (int k = 0; k < 4; ++k)
        if (base + k < N_NODES) v += counts[base + k];
    s[t] = v;
    __syncthreads();
    for (int off = 128; off > 0; off >>= 1) {
        if (t < off) s[t] += s[t + off];
        __syncthreads();
    }
    if (t == 0) blocksum[b] = s[0];
}

__global__ void scan2_kernel(const int* __restrict__ blocksum, int* __restrict__ chunk_off) {
    __shared__ int s[512];
    int t = threadIdx.x;
    int orig = (t < NCHUNK) ? blocksum[t] : 0;
    s[t] = orig;
    __syncthreads();
    for (int off = 1; off < 512; off <<= 1) {
        int v = (t >= off) ? s[t - off] : 0;
        __syncthreads();
        s[t] += v;
        __syncthreads();
    }
    if (t < NCHUNK) chunk_off[t] = s[t] - orig;   // exclusive
}

__global__ void scan3_kernel(const int* __restrict__ counts,
                             const int* __restrict__ chunk_off,
                             int* __restrict__ row_ptr,
                             int nnz) {
    __shared__ int s[256];
    int b = blockIdx.x, t = threadIdx.x;
    int base = b * CHUNK + t * 4;
    int c[4];
    int local = 0;
    #pragma unroll
    for (int k = 0; k < 4; ++k) {
        c[k] = (base + k < N_NODES) ? counts[base + k] : 0;
        local += c[k];
    }
    s[t] = local;
    __syncthreads();
    for (int off = 1; off < 256; off <<= 1) {
        int v = (t >= off) ? s[t - off] : 0;
        __syncthreads();
        s[t] += v;
        __syncthreads();
    }
    int p = chunk_off[b] + s[t] - local;
    #pragma unroll
    for (int k = 0; k < 4; ++k) {
        if (base + k < N_NODES) {
            row_ptr[base + k] = p;
            p += c[k];
        }
    }
    if (b == 0 && t == 0) row_ptr[N_NODES] = nnz;
}

__global__ void bucket_init_kernel(const int* __restrict__ row_ptr,
                                   int* __restrict__ bucket_cursor) {
    int b = blockIdx.x * blockDim.x + threadIdx.x;
    if (b < NBUCKET) bucket_cursor[b] = row_ptr[b * BROWS];
}

// ---------- Pass A: bin edges into bucket-aligned CSR ranges ----------
// payload: (.x = localrow<<19 | col, .y = val bits)
__global__ void binA_kernel(const int* __restrict__ rows,
                            const int* __restrict__ cols,
                            const float* __restrict__ vals,
                            int* __restrict__ bucket_cursor,
                            int2* __restrict__ binned,
                            int nnz) {
    __shared__ int h[NBUCKET];
    int t = threadIdx.x;
    size_t base = (size_t)blockIdx.x * EDGES_PER_BLOCK;
    for (int i = t; i < NBUCKET; i += 256) h[i] = 0;
    __syncthreads();
    #pragma unroll 4
    for (int k = 0; k < EPT; ++k) {
        size_t e = base + (size_t)k * 256 + t;
        if (e < (size_t)nnz) atomicAdd(&h[rows[e] >> 9], 1);
    }
    __syncthreads();
    for (int i = t; i < NBUCKET; i += 256) {
        int c = h[i];
        h[i] = (c > 0) ? atomicAdd(&bucket_cursor[i], c) : 0;
    }
    __syncthreads();
    #pragma unroll 4
    for (int k = 0; k < EPT; ++k) {
        size_t e = base + (size_t)k * 256 + t;
        if (e < (size_t)nnz) {
            int r = rows[e];
            int pos = atomicAdd(&h[r >> 9], 1);
            binned[pos] = make_int2(((r & (BROWS - 1)) << 19) | cols[e],
                                    __float_as_int(vals[e]));
        }
    }
}

// ---------- Pass B: within-bucket permute to exact CSR order ----------
__global__ void binB_kernel(const int* __restrict__ row_ptr,
                            const int2* __restrict__ binned,
                            int2* __restrict__ sorted) {
    __shared__ int cur[BROWS];
    int b = blockIdx.x, t = threadIdx.x;
    int row0 = b * BROWS;
    int rows_n = N_NODES - row0; if (rows_n > BROWS) rows_n = BROWS;
    for (int i = t; i < rows_n; i += 256) cur[i] = row_ptr[row0 + i];
    int beg = row_ptr[row0];
    int row_end = row0 + BROWS; if (row_end > N_NODES) row_end = N_NODES;
    int end = row_ptr[row_end];
    __syncthreads();
    for (int idx = beg + t; idx < end; idx += 256) {
        int2 e = binned[idx];
        int lr  = ((unsigned)e.x) >> 19;
        int col = e.x & 0x7FFFF;
        int pos = atomicAdd(&cur[lr], 1);
        sorted[pos] = make_int2(col, e.y);
    }
}

// ---------- row-centric SpMM: one wave per row, lane = dim, bf16 src/dst ----------
__global__ void spmm_row_kernel(const int* __restrict__ row_ptr,
                                const int2* __restrict__ sorted,
                                const unsigned short* __restrict__ srch,
                                unsigned short* __restrict__ dsth) {
    int t = blockIdx.x * blockDim.x + threadIdx.x;
    int r = t >> 6;
    int d = t & 63;
    if (r >= N_NODES) return;
    int beg = row_ptr[r];
    int end = row_ptr[r + 1];
    float acc = 0.f;

    for (int base = beg; base < end; base += 64) {
        int cnt = end - base;
        if (cnt > 64) cnt = 64;
        int   c_l = 0;
        float v_l = 0.f;
        if (base + d < end) {
            int2 e = sorted[base + d];
            c_l = e.x;
            v_l = __int_as_float(e.y);
        }
        int j = 0;
        for (; j + 8 <= cnt; j += 8) {
            int c0 = __shfl(c_l, j + 0), c1 = __shfl(c_l, j + 1);
            int c2 = __shfl(c_l, j + 2), c3 = __shfl(c_l, j + 3);
            int c4 = __shfl(c_l, j + 4), c5 = __shfl(c_l, j + 5);
            int c6 = __shfl(c_l, j + 6), c7 = __shfl(c_l, j + 7);
            float v0 = __shfl(v_l, j + 0), v1 = __shfl(v_l, j + 1);
            float v2 = __shfl(v_l, j + 2), v3 = __shfl(v_l, j + 3);
            float v4 = __shfl(v_l, j + 4), v5 = __shfl(v_l, j + 5);
            float v6 = __shfl(v_l, j + 6), v7 = __shfl(v_l, j + 7);
            float s0 = bf2f(srch[(size_t)c0 * DIM + d]);
            float s1 = bf2f(srch[(size_t)c1 * DIM + d]);
            float s2 = bf2f(srch[(size_t)c2 * DIM + d]);
            float s3 = bf2f(srch[(size_t)c3 * DIM + d]);
            float s4 = bf2f(srch[(size_t)c4 * DIM + d]);
            float s5 = bf2f(srch[(size_t)c5 * DIM + d]);
            float s6 = bf2f(srch[(size_t)c6 * DIM + d]);
            float s7 = bf2f(srch[(size_t)c7 * DIM + d]);
            acc += v0 * s0; acc += v1 * s1; acc += v2 * s2; acc += v3 * s3;
            acc += v4 * s4; acc += v5 * s5; acc += v6 * s6; acc += v7 * s7;
        }
        for (; j + 4 <= cnt; j += 4) {
            int c0 = __shfl(c_l, j + 0), c1 = __shfl(c_l, j + 1);
            int c2 = __shfl(c_l, j + 2), c3 = __shfl(c_l, j + 3);
            float v0 = __shfl(v_l, j + 0), v1 = __shfl(v_l, j + 1);
            float v2 = __shfl(v_l, j + 2), v3 = __shfl(v_l, j + 3);
            float s0 = bf2f(srch[(size_t)c0 * DIM + d]);
            float s1 = bf2f(srch[(size_t)c1 * DIM + d]);
            float s2 = bf2f(srch[(size_t)c2 * DIM + d]);
            float s3 = bf2f(srch[(size_t)c3 * DIM + d]);
            acc += v0 * s0; acc += v1 * s1; acc += v2 * s2; acc += v3 * s3;
        }
        for (; j < cnt; ++j) {
            int c = __shfl(c_l, j);
            float v = __shfl(v_l, j);
            acc += v * bf2f(srch[(size_t)c * DIM + d]);
        }
    }
    dsth[(size_t)r * DIM + d] = f2bf(acc);
}

// ---------- final: out += 0.25*(y1+y2+y3) ----------
__global__ void final_kernel(const ushort4* __restrict__ y1,
                             const ushort4* __restrict__ y2,
                             const ushort4* __restrict__ y3,
                             float4* __restrict__ out) {
    size_t i = (size_t)blockIdx.x * blockDim.x + threadIdx.x;
    if (i >= TOT_F4) return;
    ushort4 a = y1[i], b = y2[i], c = y3[i];
    float4 o = out[i];
    o.x += 0.25f * (bf2f(a.x) + bf2f(b.x) + bf2f(c.x));
    o.y += 0.25f * (bf2f(a.y) + bf2f(b.y) + bf2f(c.y));
    o.z += 0.25f * (bf2f(a.z) + bf2f(b.z) + bf2f(c.z));
    o.w += 0.25f * (bf2f(a.w) + bf2f(b.w) + bf2f(c.w));
    out[i] = o;
}

extern "C" void kernel_launch(void* const* d_in, const int* in_sizes, int n_in,
                              void* d_out, int out_size, void* d_ws, size_t ws_size,
                              hipStream_t stream) {
    const float* user = (const float*)d_in[0];
    const float* item = (const float*)d_in[1];
    const int*   rows = (const int*)d_in[2];
    const int*   cols = (const int*)d_in[3];
    const float* vals = (const float*)d_in[4];
    int nnz = in_sizes[2];

    float* out = (float*)d_out;

    // workspace layout (all offsets multiples of 16)
    char* p = (char*)d_ws;
    unsigned short* xh  = (unsigned short*)p; p += TOT_ELEMS * 2;    // 38.4 MB
    unsigned short* y1h = (unsigned short*)p; p += TOT_ELEMS * 2;    // 38.4 MB
    unsigned short* y2h = (unsigned short*)p; p += TOT_ELEMS * 2;    // 38.4 MB
    int2* binned = (int2*)p;                                         // 51.2 MB
    unsigned short* y3h = (unsigned short*)p;                        // aliases binned (binned dead before layer 3)
    p += (size_t)nnz * sizeof(int2);
    int2* sorted = (int2*)p; p += (size_t)nnz * sizeof(int2);        // 51.2 MB
    int* counts        = (int*)p; p += (size_t)N_NODES * 4;
    int* row_ptr       = (int*)p; p += (size_t)(N_NODES + 1) * 4;
    int* blocksum      = (int*)p; p += (size_t)NCHUNK * 4;
    int* chunk_off     = (int*)p; p += (size_t)NCHUNK * 4;
    int* bucket_cursor = (int*)p; p += (size_t)NBUCKET * 4;

    const int BLK = 256;
    int grid_elem = (int)((TOT_F4 + BLK - 1) / BLK);          // 18750
    int grid_node = (N_NODES + BLK - 1) / BLK;
    int grid_edge = (nnz + BLK - 1) / BLK;
    int grid_binA = (nnz + EDGES_PER_BLOCK - 1) / EDGES_PER_BLOCK;   // 782
    int grid_rows = (N_NODES * 64 + BLK - 1) / BLK;           // 75000

    init_kernel<<<grid_elem, BLK, 0, stream>>>(
        (const float4*)user, (const float4*)item, (float4*)out, (ushort4*)xh);

    // row_ptr build
    zero_counts_kernel<<<grid_node, BLK, 0, stream>>>(counts);
    hist_kernel<<<grid_edge, BLK, 0, stream>>>(rows, counts, nnz);
    scan1_kernel<<<NCHUNK, BLK, 0, stream>>>(counts, blocksum);
    scan2_kernel<<<1, 512, 0, stream>>>(blocksum, chunk_off);
    scan3_kernel<<<NCHUNK, BLK, 0, stream>>>(counts, chunk_off, row_ptr, nnz);

    // two-pass binned sort into CSR order
    bucket_init_kernel<<<(NBUCKET + BLK - 1) / BLK, BLK, 0, stream>>>(row_ptr, bucket_cursor);
    binA_kernel<<<grid_binA, BLK, 0, stream>>>(rows, cols, vals, bucket_cursor, binned, nnz);
    binB_kernel<<<NBUCKET, BLK, 0, stream>>>(row_ptr, binned, sorted);

    // 3 propagation layers (bf16 state), out accumulated at the end
    spmm_row_kernel<<<grid_rows, BLK, 0, stream>>>(row_ptr, sorted, xh,  y1h);
    spmm_row_kernel<<<grid_rows, BLK, 0, stream>>>(row_ptr, sorted, y1h, y2h);
    spmm_row_kernel<<<grid_rows, BLK, 0, stream>>>(row_ptr, sorted, y2h, y3h);

    final_kernel<<<grid_elem, BLK, 0, stream>>>(
        (const ushort4*)y1h, (const ushort4*)y2h, (const ushort4*)y3h, (float4*)out);
}

// Round 5
// 942.566 us; speedup vs baseline: 4.7147x; 1.2245x over previous
//
#include <hip/hip_runtime.h>
#include <hip/hip_bf16.h>

#define N_USERS 100000
#define N_ITEMS 200000
#define N_NODES 300000
#define DIM 64

#define TOT_ELEMS ((size_t)N_NODES * DIM)          // 19,200,000 floats
#define TOT_F4    (TOT_ELEMS / 4)                  // 4,800,000
#define USER_F4   (((size_t)N_USERS * DIM) / 4)    // 1,600,000

#define BROWS 512
#define NBUCKET ((N_NODES + BROWS - 1) / BROWS)    // 586
#define EPT 32
#define EDGES_PER_BLOCK (EPT * 256)                // 8192

__device__ __forceinline__ float bf2f(unsigned short u) {
    return __uint_as_float((unsigned int)u << 16);
}
__device__ __forceinline__ unsigned short f2bf(float f) {
    __hip_bfloat16 h = __float2bfloat16(f);   // RNE
    return *reinterpret_cast<unsigned short*>(&h);
}

// ---------- init: out = 0.25*concat(user,item); xh = bf16(concat) ----------
__global__ void init_kernel(const float4* __restrict__ user,
                            const float4* __restrict__ item,
                            float4* __restrict__ out,
                            ushort4* __restrict__ xh) {
    size_t i = (size_t)blockIdx.x * blockDim.x + threadIdx.x;
    if (i >= TOT_F4) return;
    float4 v = (i < USER_F4) ? user[i] : item[i - USER_F4];
    float4 o;
    o.x = 0.25f * v.x; o.y = 0.25f * v.y; o.z = 0.25f * v.z; o.w = 0.25f * v.w;
    out[i] = o;
    ushort4 h;
    h.x = f2bf(v.x); h.y = f2bf(v.y); h.z = f2bf(v.z); h.w = f2bf(v.w);
    xh[i] = h;
}

// ---------- bucket-level histogram (586 counters, cache-resident) ----------
__global__ void zero_buckets_kernel(int* __restrict__ bucket_count) {
    int i = blockIdx.x * blockDim.x + threadIdx.x;
    if (i < NBUCKET) bucket_count[i] = 0;
}

__global__ void bucket_hist_kernel(const int* __restrict__ rows,
                                   int* __restrict__ bucket_count, int nnz) {
    __shared__ int h[NBUCKET];
    int t = threadIdx.x;
    size_t base = (size_t)blockIdx.x * EDGES_PER_BLOCK;
    for (int i = t; i < NBUCKET; i += 256) h[i] = 0;
    __syncthreads();
    #pragma unroll 4
    for (int k = 0; k < EPT; ++k) {
        size_t e = base + (size_t)k * 256 + t;
        if (e < (size_t)nnz) atomicAdd(&h[rows[e] >> 9], 1);
    }
    __syncthreads();
    for (int i = t; i < NBUCKET; i += 256) {
        int c = h[i];
        if (c) atomicAdd(&bucket_count[i], c);
    }
}

// exclusive scan of bucket counts -> bucket_base[0..NBUCKET], seed bucket_cursor
__global__ void bucket_scan_kernel(const int* __restrict__ bucket_count,
                                   int* __restrict__ bucket_base,
                                   int* __restrict__ bucket_cursor, int nnz) {
    __shared__ int s[1024];
    int t = threadIdx.x;
    int orig = (t < NBUCKET) ? bucket_count[t] : 0;
    s[t] = orig;
    __syncthreads();
    for (int off = 1; off < 1024; off <<= 1) {
        int v = (t >= off) ? s[t - off] : 0;
        __syncthreads();
        s[t] += v;
        __syncthreads();
    }
    if (t < NBUCKET) {
        int excl = s[t] - orig;
        bucket_base[t]   = excl;
        bucket_cursor[t] = excl;
    }
    if (t == 0) bucket_base[NBUCKET] = nnz;
}

// ---------- Pass A: bin edges into bucket ranges ----------
// payload: (.x = localrow<<19 | col, .y = val bits)
__global__ void binA_kernel(const int* __restrict__ rows,
                            const int* __restrict__ cols,
                            const float* __restrict__ vals,
                            int* __restrict__ bucket_cursor,
                            int2* __restrict__ binned,
                            int nnz) {
    __shared__ int h[NBUCKET];
    int t = threadIdx.x;
    size_t base = (size_t)blockIdx.x * EDGES_PER_BLOCK;
    for (int i = t; i < NBUCKET; i += 256) h[i] = 0;
    __syncthreads();
    #pragma unroll 4
    for (int k = 0; k < EPT; ++k) {
        size_t e = base + (size_t)k * 256 + t;
        if (e < (size_t)nnz) atomicAdd(&h[rows[e] >> 9], 1);
    }
    __syncthreads();
    for (int i = t; i < NBUCKET; i += 256) {
        int c = h[i];
        h[i] = (c > 0) ? atomicAdd(&bucket_cursor[i], c) : 0;
    }
    __syncthreads();
    #pragma unroll 4
    for (int k = 0; k < EPT; ++k) {
        size_t e = base + (size_t)k * 256 + t;
        if (e < (size_t)nnz) {
            int r = rows[e];
            int pos = atomicAdd(&h[r >> 9], 1);
            binned[pos] = make_int2(((r & (BROWS - 1)) << 19) | cols[e],
                                    __float_as_int(vals[e]));
        }
    }
}

// ---------- Pass B: per-row histogram + scan -> row_ptr, then permute ----------
__global__ void binB_kernel(const int* __restrict__ bucket_base,
                            const int2* __restrict__ binned,
                            int2* __restrict__ sorted,
                            int* __restrict__ row_ptr,
                            int nnz) {
    __shared__ int cnt[BROWS];
    __shared__ int cur[BROWS];
    __shared__ int s[256];
    int b = blockIdx.x, t = threadIdx.x;
    int beg = bucket_base[b];
    int end = bucket_base[b + 1];
    int row0 = b * BROWS;
    for (int i = t; i < BROWS; i += 256) cnt[i] = 0;
    __syncthreads();
    // per-row histogram of this bucket's edges
    for (int idx = beg + t; idx < end; idx += 256) {
        int lr = ((unsigned)binned[idx].x) >> 19;
        atomicAdd(&cnt[lr], 1);
    }
    __syncthreads();
    // exclusive scan of 512 counts (2 per thread)
    int c0 = cnt[2 * t], c1 = cnt[2 * t + 1];
    int local = c0 + c1;
    s[t] = local;
    __syncthreads();
    for (int off = 1; off < 256; off <<= 1) {
        int v = (t >= off) ? s[t - off] : 0;
        __syncthreads();
        s[t] += v;
        __syncthreads();
    }
    int excl = beg + s[t] - local;
    int r0 = row0 + 2 * t;
    if (r0 < N_NODES)     row_ptr[r0]     = excl;
    if (r0 + 1 < N_NODES) row_ptr[r0 + 1] = excl + c0;
    cur[2 * t]     = excl;
    cur[2 * t + 1] = excl + c0;
    __syncthreads();
    // permute to exact CSR order
    for (int idx = beg + t; idx < end; idx += 256) {
        int2 e = binned[idx];
        int lr  = ((unsigned)e.x) >> 19;
        int col = e.x & 0x7FFFF;
        int pos = atomicAdd(&cur[lr], 1);
        sorted[pos] = make_int2(col, e.y);
    }
    if (b == 0 && t == 0) row_ptr[N_NODES] = nnz;
}

// ---------- row-centric SpMM: one wave per row, lane = dim, bf16 src/dst ----------
__global__ void spmm_row_kernel(const int* __restrict__ row_ptr,
                                const int2* __restrict__ sorted,
                                const unsigned short* __restrict__ srch,
                                unsigned short* __restrict__ dsth) {
    int t = blockIdx.x * blockDim.x + threadIdx.x;
    int r = t >> 6;
    int d = t & 63;
    if (r >= N_NODES) return;
    int beg = row_ptr[r];
    int end = row_ptr[r + 1];
    float acc = 0.f;

    for (int base = beg; base < end; base += 64) {
        int cnt = end - base;
        if (cnt > 64) cnt = 64;
        int   c_l = 0;
        float v_l = 0.f;
        if (base + d < end) {
            int2 e = sorted[base + d];
            c_l = e.x;
            v_l = __int_as_float(e.y);
        }
        int j = 0;
        for (; j + 8 <= cnt; j += 8) {
            int c0 = __shfl(c_l, j + 0), c1 = __shfl(c_l, j + 1);
            int c2 = __shfl(c_l, j + 2), c3 = __shfl(c_l, j + 3);
            int c4 = __shfl(c_l, j + 4), c5 = __shfl(c_l, j + 5);
            int c6 = __shfl(c_l, j + 6), c7 = __shfl(c_l, j + 7);
            float v0 = __shfl(v_l, j + 0), v1 = __shfl(v_l, j + 1);
            float v2 = __shfl(v_l, j + 2), v3 = __shfl(v_l, j + 3);
            float v4 = __shfl(v_l, j + 4), v5 = __shfl(v_l, j + 5);
            float v6 = __shfl(v_l, j + 6), v7 = __shfl(v_l, j + 7);
            float s0 = bf2f(srch[(size_t)c0 * DIM + d]);
            float s1 = bf2f(srch[(size_t)c1 * DIM + d]);
            float s2 = bf2f(srch[(size_t)c2 * DIM + d]);
            float s3 = bf2f(srch[(size_t)c3 * DIM + d]);
            float s4 = bf2f(srch[(size_t)c4 * DIM + d]);
            float s5 = bf2f(srch[(size_t)c5 * DIM + d]);
            float s6 = bf2f(srch[(size_t)c6 * DIM + d]);
            float s7 = bf2f(srch[(size_t)c7 * DIM + d]);
            acc += v0 * s0; acc += v1 * s1; acc += v2 * s2; acc += v3 * s3;
            acc += v4 * s4; acc += v5 * s5; acc += v6 * s6; acc += v7 * s7;
        }
        for (; j + 4 <= cnt; j += 4) {
            int c0 = __shfl(c_l, j + 0), c1 = __shfl(c_l, j + 1);
            int c2 = __shfl(c_l, j + 2), c3 = __shfl(c_l, j + 3);
            float v0 = __shfl(v_l, j + 0), v1 = __shfl(v_l, j + 1);
            float v2 = __shfl(v_l, j + 2), v3 = __shfl(v_l, j + 3);
            float s0 = bf2f(srch[(size_t)c0 * DIM + d]);
            float s1 = bf2f(srch[(size_t)c1 * DIM + d]);
            float s2 = bf2f(srch[(size_t)c2 * DIM + d]);
            float s3 = bf2f(srch[(size_t)c3 * DIM + d]);
            acc += v0 * s0; acc += v1 * s1; acc += v2 * s2; acc += v3 * s3;
        }
        for (; j < cnt; ++j) {
            int c = __shfl(c_l, j);
            float v = __shfl(v_l, j);
            acc += v * bf2f(srch[(size_t)c * DIM + d]);
        }
    }
    dsth[(size_t)r * DIM + d] = f2bf(acc);
}

// ---------- final: out += 0.25*(y1+y2+y3) ----------
__global__ void final_kernel(const ushort4* __restrict__ y1,
                             const ushort4* __restrict__ y2,
                             const ushort4* __restrict__ y3,
                             float4* __restrict__ out) {
    size_t i = (size_t)blockIdx.x * blockDim.x + threadIdx.x;
    if (i >= TOT_F4) return;
    ushort4 a = y1[i], b = y2[i], c = y3[i];
    float4 o = out[i];
    o.x += 0.25f * (bf2f(a.x) + bf2f(b.x) + bf2f(c.x));
    o.y += 0.25f * (bf2f(a.y) + bf2f(b.y) + bf2f(c.y));
    o.z += 0.25f * (bf2f(a.z) + bf2f(b.z) + bf2f(c.z));
    o.w += 0.25f * (bf2f(a.w) + bf2f(b.w) + bf2f(c.w));
    out[i] = o;
}

extern "C" void kernel_launch(void* const* d_in, const int* in_sizes, int n_in,
                              void* d_out, int out_size, void* d_ws, size_t ws_size,
                              hipStream_t stream) {
    const float* user = (const float*)d_in[0];
    const float* item = (const float*)d_in[1];
    const int*   rows = (const int*)d_in[2];
    const int*   cols = (const int*)d_in[3];
    const float* vals = (const float*)d_in[4];
    int nnz = in_sizes[2];

    float* out = (float*)d_out;

    // workspace layout (all offsets multiples of 16)
    char* p = (char*)d_ws;
    unsigned short* xh  = (unsigned short*)p; p += TOT_ELEMS * 2;    // 38.4 MB
    unsigned short* y1h = (unsigned short*)p; p += TOT_ELEMS * 2;    // 38.4 MB
    unsigned short* y2h = (unsigned short*)p; p += TOT_ELEMS * 2;    // 38.4 MB
    int2* binned = (int2*)p;                                         // 51.2 MB
    unsigned short* y3h = (unsigned short*)p;                        // aliases binned (binned dead before layer 3)
    p += (size_t)nnz * sizeof(int2);
    int2* sorted = (int2*)p; p += (size_t)nnz * sizeof(int2);        // 51.2 MB
    int* row_ptr       = (int*)p; p += (size_t)(N_NODES + 1) * 4;
    int* bucket_count  = (int*)p; p += (size_t)NBUCKET * 4;
    int* bucket_base   = (int*)p; p += (size_t)(NBUCKET + 1) * 4;
    int* bucket_cursor = (int*)p; p += (size_t)NBUCKET * 4;

    const int BLK = 256;
    int grid_elem = (int)((TOT_F4 + BLK - 1) / BLK);                 // 18750
    int grid_binA = (nnz + EDGES_PER_BLOCK - 1) / EDGES_PER_BLOCK;   // 782
    int grid_rows = (N_NODES * 64 + BLK - 1) / BLK;                  // 75000

    init_kernel<<<grid_elem, BLK, 0, stream>>>(
        (const float4*)user, (const float4*)item, (float4*)out, (ushort4*)xh);

    // bucket offsets (no per-row global histogram)
    zero_buckets_kernel<<<(NBUCKET + BLK - 1) / BLK, BLK, 0, stream>>>(bucket_count);
    bucket_hist_kernel<<<grid_binA, BLK, 0, stream>>>(rows, bucket_count, nnz);
    bucket_scan_kernel<<<1, 1024, 0, stream>>>(bucket_count, bucket_base, bucket_cursor, nnz);

    // two-pass binned sort into CSR order (binB also emits row_ptr)
    binA_kernel<<<grid_binA, BLK, 0, stream>>>(rows, cols, vals, bucket_cursor, binned, nnz);
    binB_kernel<<<NBUCKET, BLK, 0, stream>>>(bucket_base, binned, sorted, row_ptr, nnz);

    // 3 propagation layers (bf16 state), out accumulated at the end
    spmm_row_kernel<<<grid_rows, BLK, 0, stream>>>(row_ptr, sorted, xh,  y1h);
    spmm_row_kernel<<<grid_rows, BLK, 0, stream>>>(row_ptr, sorted, y1h, y2h);
    spmm_row_kernel<<<grid_rows, BLK, 0, stream>>>(row_ptr, sorted, y2h, y3h);

    final_kernel<<<grid_elem, BLK, 0, stream>>>(
        (const ushort4*)y1h, (const ushort4*)y2h, (const ushort4*)y3h, (float4*)out);
}